// Round 4
// baseline (132.760 us; speedup 1.0000x reference)
//
#include <hip/hip_runtime.h>
#include <math.h>

constexpr int Dn = 4096;     // C*H*W (row length)
constexpr int Bn = 4096;     // batch
constexpr int NCLS = 10;

// Workspace layout (float/int units)
constexpr int OFF_CUR   = 0;      // 10 ints: class counts
constexpr int OFF_CE    = 10;     // 1 float: CE sum
constexpr int OFF_XS    = 11;     // 1 float: sum of S^2 (zeroed)
constexpr int OFF_NCH   = 12;     // 1 int: number of chunks
constexpr int OFF_DONE  = 13;     // 1 int: pass34 ticket (zeroed)
constexpr int OFF_CHS   = 16;     // 11 ints: per-class chunk range starts
constexpr int OFF_ORD   = 32;     // 10*4096 ints: per-class sample lists
constexpr int OFF_CHMAP = 41000;  // up to ~270 ints: chunk -> (class<<16)|start
constexpr int OFF_P     = 41472;  // partials: maxch * 4096 floats (16B aligned)

// ---------------------------------------------------------------- pass 0
// Single block, 1024 threads. CE + argmax + per-class ordering + chunk map.
// No global atomics: per-wave ballot ranks + LDS histograms.
__global__ __launch_bounds__(1024) void pass0_ce_order_sched(
    const float* __restrict__ outputs, const int* __restrict__ y,
    float* __restrict__ ws, int CH)
{
    const int t = threadIdx.x;
    const int w = t >> 6, lane = t & 63;
    int* wsi = (int*)ws;

    __shared__ int whist[16][NCLS];          // per-wave per-class counts
    __shared__ int wbase[16][NCLS];          // per-wave per-class exclusive base
    __shared__ int cnt[NCLS];
    __shared__ float sce[16];
    __shared__ unsigned short srec[Bn];      // (am<<12) | within-wave-class pos

    if (t < 16 * NCLS) ((int*)whist)[t] = 0;
    __syncthreads();

    float ce_acc = 0.f;
    #pragma unroll
    for (int r = 0; r < 4; ++r) {
        const int i = r * 1024 + t;
        const float* o = outputs + (size_t)i * NCLS;
        float m = o[0]; int am = 0;
        #pragma unroll
        for (int k = 1; k < NCLS; ++k) { float ok = o[k]; if (ok > m) { m = ok; am = k; } }
        float se = 0.f;
        #pragma unroll
        for (int k = 0; k < NCLS; ++k) se += expf(o[k] - m);
        ce_acc += m + logf(se) - o[y[i]];

        // wave ballot: rank within (wave, class) for this round
        int myrank = 0, mycnt = 0;
        #pragma unroll
        for (int c = 0; c < NCLS; ++c) {
            unsigned long long mk = __ballot(am == c);
            if (am == c) myrank = __popcll(mk & ((1ull << lane) - 1ull));
            if (lane == c) mycnt = (int)__popcll(mk);
        }
        int localpos = whist[w][am] + myrank;      // same-wave LDS, program order
        if (lane < NCLS) whist[w][lane] += mycnt;
        srec[i] = (unsigned short)((am << 12) | localpos);
    }

    #pragma unroll
    for (int off = 32; off; off >>= 1) ce_acc += __shfl_down(ce_acc, off, 64);
    if (lane == 0) sce[w] = ce_acc;
    __syncthreads();

    if (t < NCLS) {                 // scan over waves for class t
        int s = 0;
        for (int w2 = 0; w2 < 16; ++w2) { wbase[w2][t] = s; s += whist[w2][t]; }
        cnt[t] = s;
    }
    __syncthreads();

    if (t == 0) {
        float cs = 0.f;
        for (int w2 = 0; w2 < 16; ++w2) cs += sce[w2];
        ws[OFF_CE] = cs;
        int nch = 0;
        for (int c = 0; c < NCLS; ++c) {
            wsi[OFF_CUR + c] = cnt[c];
            wsi[OFF_CHS + c] = nch;
            for (int s = 0; s < cnt[c]; s += CH)
                wsi[OFF_CHMAP + nch++] = (c << 16) | s;
        }
        wsi[OFF_CHS + NCLS] = nch;
        wsi[OFF_NCH] = nch;
    }
    __syncthreads();

    #pragma unroll
    for (int r = 0; r < 4; ++r) {
        const int i = r * 1024 + t;
        unsigned short rec = srec[i];
        int am = rec >> 12, lp = rec & 0xFFF;
        wsi[OFF_ORD + am * Bn + wbase[w][am] + lp] = i;
    }
}

// ---------------------------------------------------------------- pass 12
// Fused per-row stats + class-weighted accumulate. One chunk (<=CH same-class
// rows) per block; each WAVE owns whole rows (wave-only reductions), full row
// in registers (16 float4/lane), grad read exactly once.
__global__ __launch_bounds__(256) void pass12_fused(
    const float* __restrict__ grad, float* __restrict__ ws, int CH)
{
    const int* wsi = (const int*)ws;
    const int chunk = blockIdx.x;
    if (chunk >= wsi[OFF_NCH]) return;           // uniform per block

    const int t = threadIdx.x;
    const int w = t >> 6, lane = t & 63;

    const int e  = wsi[OFF_CHMAP + chunk];
    const int c  = e >> 16;
    const int s0 = e & 0xFFFF;
    const int m  = min(CH, wsi[OFF_CUR + c] - s0);

    float4 acc[16];
    #pragma unroll
    for (int k = 0; k < 16; ++k) acc[k] = make_float4(0.f, 0.f, 0.f, 0.f);
    float sb = 0.f;

    const float4* g4 = (const float4*)grad;
    for (int r = w; r < m; r += 4) {
        const int idx = wsi[OFF_ORD + c * Bn + s0 + r];
        const float4* row = g4 + (size_t)idx * (Dn / 4);
        float4 v[16];
        #pragma unroll
        for (int k = 0; k < 16; ++k) v[k] = row[k * 64 + lane];

        // wave min (butterfly -> all lanes)
        float mn = fminf(fminf(v[0].x, v[0].y), fminf(v[0].z, v[0].w));
        #pragma unroll
        for (int k = 1; k < 16; ++k)
            mn = fminf(mn, fminf(fminf(v[k].x, v[k].y), fminf(v[k].z, v[k].w)));
        #pragma unroll
        for (int off = 1; off < 64; off <<= 1)
            mn = fminf(mn, __shfl_xor(mn, off, 64));

        // wave sum of squares of (g - mn)
        float ss = 0.f;
        #pragma unroll
        for (int k = 0; k < 16; ++k) {
            float dx = v[k].x - mn, dy = v[k].y - mn;
            float dz = v[k].z - mn, dw = v[k].w - mn;
            ss += dx * dx + dy * dy + dz * dz + dw * dw;
        }
        #pragma unroll
        for (int off = 1; off < 64; off <<= 1)
            ss += __shfl_xor(ss, off, 64);

        const float a = 1.0f / sqrtf(ss);    // min-max range cancels under L2
        sb += -mn * a;                       // b term, uniform per row
        #pragma unroll
        for (int k = 0; k < 16; ++k) {
            acc[k].x = fmaf(v[k].x, a, acc[k].x);
            acc[k].y = fmaf(v[k].y, a, acc[k].y);
            acc[k].z = fmaf(v[k].z, a, acc[k].z);
            acc[k].w = fmaf(v[k].w, a, acc[k].w);
        }
    }
    #pragma unroll
    for (int k = 0; k < 16; ++k) {
        acc[k].x += sb; acc[k].y += sb; acc[k].z += sb; acc[k].w += sb;
    }

    // combine 4 waves in LDS (staged adds), then one coalesced 16 KB store
    __shared__ float4 sacc[Dn / 4];
    if (w == 0) {
        #pragma unroll
        for (int k = 0; k < 16; ++k) sacc[k * 64 + lane] = acc[k];
    }
    __syncthreads();
    #pragma unroll
    for (int ww = 1; ww < 4; ++ww) {
        if (w == ww) {
            #pragma unroll
            for (int k = 0; k < 16; ++k) {
                float4 s = sacc[k * 64 + lane];
                s.x += acc[k].x; s.y += acc[k].y; s.z += acc[k].z; s.w += acc[k].w;
                sacc[k * 64 + lane] = s;
            }
        }
        __syncthreads();
    }
    float4* Pc = (float4*)(ws + OFF_P) + (size_t)chunk * (Dn / 4);
    #pragma unroll
    for (int k = 0; k < 4; ++k) Pc[k * 256 + t] = sacc[k * 256 + t];
}

// ---------------------------------------------------------------- pass 34
// Reduce chunk partials per class, square, sum; last block finalizes.
__global__ __launch_bounds__(256) void pass34_final(
    float* __restrict__ ws, float* __restrict__ out)
{
    const int t = threadIdx.x;
    const int idx = blockIdx.x * 256 + t;    // 0 .. 40959
    const int c = idx >> 12;                 // class (uniform per block)
    const int j = idx & (Dn - 1);
    const int w = t >> 6, lane = t & 63;
    const int* wsi = (const int*)ws;

    const int cs  = wsi[OFF_CHS + c];
    const int ce2 = wsi[OFF_CHS + c + 1];
    const float* P = ws + OFF_P;

    float s = 0.f;
    for (int ch = cs; ch < ce2; ++ch)
        s += P[(size_t)ch * Dn + j];
    float p = s * s;

    #pragma unroll
    for (int off = 32; off; off >>= 1) p += __shfl_down(p, off, 64);
    __shared__ float sr[4];
    if (lane == 0) sr[w] = p;
    __syncthreads();
    if (t == 0) {
        atomicAdd(&ws[OFF_XS], sr[0] + sr[1] + sr[2] + sr[3]);
        __threadfence();
        int ticket = atomicAdd(&((int*)ws)[OFF_DONE], 1);
        if (ticket == (NCLS * Dn / 256) - 1) {
            float xs = atomicAdd(&ws[OFF_XS], 0.0f);   // coherent read
            const int* n = wsi + OFF_CUR;
            double n2 = 0.0;
            #pragma unroll
            for (int k = 0; k < NCLS; ++k) { double nc = (double)n[k]; n2 += nc * nc; }
            double xloss = (n2 - (double)xs) / (2.0 * (double)Bn);
            double celoss = (double)ws[OFF_CE] / (double)Bn;
            out[0] = (float)(celoss + xloss);
        }
    }
}

extern "C" void kernel_launch(void* const* d_in, const int* in_sizes, int n_in,
                              void* d_out, int out_size, void* d_ws, size_t ws_size,
                              hipStream_t stream)
{
    const float* outputs = (const float*)d_in[0];   // [4096,10] f32
    const float* grad    = (const float*)d_in[1];   // [4096,1,64,64] f32
    const int*   y       = (const int*)d_in[2];     // [4096] i32
    float* ws  = (float*)d_ws;
    float* out = (float*)d_out;

    // pick chunk size CH (multiple of 4) so partials fit in ws
    const size_t availf = ws_size / sizeof(float);
    const int cands[6] = {16, 32, 64, 128, 256, 512};
    int CH = 512, maxch = Bn / 512 + NCLS;
    for (int k = 0; k < 6; ++k) {
        int mc = Bn / cands[k] + NCLS;
        size_t need = (size_t)OFF_P + (size_t)mc * Dn;
        if (need <= availf) { CH = cands[k]; maxch = mc; break; }
    }

    hipMemsetAsync(d_ws, 0, 128, stream);   // XS, DONE (and header)
    pass0_ce_order_sched<<<1, 1024, 0, stream>>>(outputs, y, ws, CH);
    pass12_fused<<<maxch, 256, 0, stream>>>(grad, ws, CH);
    pass34_final<<<NCLS * Dn / 256, 256, 0, stream>>>(ws, out);
}

// Round 6
// 118.357 us; speedup vs baseline: 1.1217x; 1.1217x over previous
//
#include <hip/hip_runtime.h>
#include <math.h>

constexpr int Dn = 4096;     // C*H*W (row length)
constexpr int Bn = 4096;     // batch
constexpr int NCLS = 10;
constexpr int CH = 4;        // rows per chunk == waves per pass12 block
constexpr int MAXCH = Bn / CH + NCLS;   // 1034 grid upper bound

// Workspace layout (float/int units)
constexpr int OFF_CUR  = 0;      // 10 ints: class cursors -> counts
constexpr int OFF_CE   = 10;     // 1 float: CE sum
constexpr int OFF_XS   = 11;     // 1 float: sum of S^2
constexpr int OFF_DONE = 12;     // 1 int: ticket
constexpr int OFF_ORD  = 16;     // 10*4096 ints: per-class sample lists
constexpr int OFF_P    = 41024;  // partials: MAXCH * 4096 floats (16B aligned)

// ---------------------------------------------------------------- pass 0
// CE + argmax + per-class ordering. 16 blocks x 256, one sample/thread.
// LDS-atomic rank within block, one global cursor atomic per (block,class).
__global__ __launch_bounds__(256) void pass0_ce_order(
    const float* __restrict__ outputs, const int* __restrict__ y,
    float* __restrict__ ws)
{
    const int t = threadIdx.x;
    const int i = blockIdx.x * 256 + t;
    const int w = t >> 6, lane = t & 63;
    int* wsi = (int*)ws;

    __shared__ int hist[NCLS];
    __shared__ int lbase[NCLS];
    __shared__ float sce[4];
    if (t < NCLS) hist[t] = 0;
    __syncthreads();

    const float* o = outputs + (size_t)i * NCLS;
    float m = o[0]; int am = 0;
    #pragma unroll
    for (int k = 1; k < NCLS; ++k) { float ok = o[k]; if (ok > m) { m = ok; am = k; } }
    float se = 0.f;
    #pragma unroll
    for (int k = 0; k < NCLS; ++k) se += expf(o[k] - m);
    float ce = m + logf(se) - o[y[i]];

    int rank = atomicAdd(&hist[am], 1);      // LDS atomic

    #pragma unroll
    for (int off = 32; off; off >>= 1) ce += __shfl_down(ce, off, 64);
    if (lane == 0) sce[w] = ce;
    __syncthreads();

    if (t < NCLS) lbase[t] = atomicAdd(&wsi[OFF_CUR + t], hist[t]);
    if (t == 0) atomicAdd(&ws[OFF_CE], sce[0] + sce[1] + sce[2] + sce[3]);
    __syncthreads();

    wsi[OFF_ORD + am * Bn + lbase[am] + rank] = i;
}

// ---------------------------------------------------------------- pass 12
// Fused stats + accumulate, grad read ONCE. One chunk (<=4 same-class rows)
// per block, ONE ROW PER WAVE (no acc[] array -> lower VGPR, high occupancy).
// Chunk map derived inline from class counts.
__global__ __launch_bounds__(256) void pass12_fused(
    const float* __restrict__ grad, float* __restrict__ ws)
{
    const int* wsi = (const int*)ws;
    const int t = threadIdx.x, w = t >> 6, lane = t & 63;

    // inline chunk map: blockIdx.x -> (class c, start s0, class count cnt)
    int c = -1, s0 = 0, cnt = 0;
    {
        int b = (int)blockIdx.x, acc = 0;
        #pragma unroll
        for (int k = 0; k < NCLS; ++k) {
            int n = wsi[OFF_CUR + k];
            int nch = (n + CH - 1) / CH;
            if (c < 0 && b < acc + nch) { c = k; s0 = (b - acc) * CH; cnt = n; }
            acc += nch;
        }
    }
    if (c < 0) return;                        // uniform: block beyond last chunk
    const int m = min(CH, cnt - s0);

    float4 v[16];
    if (w < m) {
        const int idx = wsi[OFF_ORD + c * Bn + s0 + w];
        const float4* row = (const float4*)grad + (size_t)idx * (Dn / 4);
        #pragma unroll
        for (int k = 0; k < 16; ++k) v[k] = row[k * 64 + lane];

        // wave min (butterfly)
        float mn = fminf(fminf(v[0].x, v[0].y), fminf(v[0].z, v[0].w));
        #pragma unroll
        for (int k = 1; k < 16; ++k)
            mn = fminf(mn, fminf(fminf(v[k].x, v[k].y), fminf(v[k].z, v[k].w)));
        #pragma unroll
        for (int off = 1; off < 64; off <<= 1)
            mn = fminf(mn, __shfl_xor(mn, off, 64));

        // wave sum of squares of (g - mn)
        float ss = 0.f;
        #pragma unroll
        for (int k = 0; k < 16; ++k) {
            float dx = v[k].x - mn, dy = v[k].y - mn;
            float dz = v[k].z - mn, dw = v[k].w - mn;
            ss += dx * dx + dy * dy + dz * dz + dw * dw;
        }
        #pragma unroll
        for (int off = 1; off < 64; off <<= 1)
            ss += __shfl_xor(ss, off, 64);

        const float a = 1.0f / sqrtf(ss);     // min-max range cancels under L2
        const float b = -mn * a;
        #pragma unroll
        for (int k = 0; k < 16; ++k) {
            v[k].x = fmaf(v[k].x, a, b);
            v[k].y = fmaf(v[k].y, a, b);
            v[k].z = fmaf(v[k].z, a, b);
            v[k].w = fmaf(v[k].w, a, b);
        }
    } else {
        #pragma unroll
        for (int k = 0; k < 16; ++k) v[k] = make_float4(0.f, 0.f, 0.f, 0.f);
    }

    // pairwise combine: w2->buf0, w3->buf1; w0+=buf0; w1+=buf1->buf1; w0+=buf1
    __shared__ float4 buf0[1024];   // 16 KB
    __shared__ float4 buf1[1024];   // 16 KB
    if (w == 2) {
        #pragma unroll
        for (int k = 0; k < 16; ++k) buf0[k * 64 + lane] = v[k];
    }
    if (w == 3) {
        #pragma unroll
        for (int k = 0; k < 16; ++k) buf1[k * 64 + lane] = v[k];
    }
    __syncthreads();
    if (w == 0) {
        #pragma unroll
        for (int k = 0; k < 16; ++k) {
            float4 u = buf0[k * 64 + lane];
            v[k].x += u.x; v[k].y += u.y; v[k].z += u.z; v[k].w += u.w;
        }
    }
    if (w == 1) {
        #pragma unroll
        for (int k = 0; k < 16; ++k) {
            float4 u = buf1[k * 64 + lane];
            v[k].x += u.x; v[k].y += u.y; v[k].z += u.z; v[k].w += u.w;
            buf1[k * 64 + lane] = v[k];       // same-wave RMW: safe
        }
    }
    __syncthreads();
    if (w == 0) {
        float4* Pc = (float4*)(ws + OFF_P) + (size_t)blockIdx.x * (Dn / 4);
        #pragma unroll
        for (int k = 0; k < 16; ++k) {
            float4 u = buf1[k * 64 + lane];
            v[k].x += u.x; v[k].y += u.y; v[k].z += u.z; v[k].w += u.w;
            Pc[k * 64 + lane] = v[k];
        }
    }
}

// ---------------------------------------------------------------- pass 34
// Reduce chunk partials per class, square, sum; last block finalizes.
__global__ __launch_bounds__(256) void pass34_final(
    float* __restrict__ ws, float* __restrict__ out)
{
    const int t = threadIdx.x;
    const int idx = blockIdx.x * 256 + t;    // 0 .. 40959
    const int c = idx >> 12;                 // class (uniform per block)
    const int j = idx & (Dn - 1);
    const int w = t >> 6, lane = t & 63;
    const int* wsi = (const int*)ws;

    int cs = 0, ce2 = 0;
    {
        int acc = 0;
        #pragma unroll
        for (int k = 0; k < NCLS; ++k) {
            int nch = (wsi[OFF_CUR + k] + CH - 1) / CH;
            if (k == c) { cs = acc; ce2 = acc + nch; }
            acc += nch;
        }
    }

    const float* P = ws + OFF_P;
    float s = 0.f;
    int ch = cs;
    for (; ch + 4 <= ce2; ch += 4)
        s += P[(size_t)(ch + 0) * Dn + j] + P[(size_t)(ch + 1) * Dn + j]
           + P[(size_t)(ch + 2) * Dn + j] + P[(size_t)(ch + 3) * Dn + j];
    for (; ch < ce2; ++ch) s += P[(size_t)ch * Dn + j];
    float p = s * s;

    #pragma unroll
    for (int off = 32; off; off >>= 1) p += __shfl_down(p, off, 64);
    __shared__ float sr[4];
    if (lane == 0) sr[w] = p;
    __syncthreads();
    if (t == 0) {
        atomicAdd(&ws[OFF_XS], sr[0] + sr[1] + sr[2] + sr[3]);
        __threadfence();
        int ticket = atomicAdd(&((int*)ws)[OFF_DONE], 1);
        if (ticket == (NCLS * Dn / 256) - 1) {
            float xs = atomicAdd(&ws[OFF_XS], 0.0f);   // coherent read
            const int* n = wsi + OFF_CUR;
            double n2 = 0.0;
            #pragma unroll
            for (int k = 0; k < NCLS; ++k) { double nc = (double)n[k]; n2 += nc * nc; }
            double xloss = (n2 - (double)xs) / (2.0 * (double)Bn);
            double celoss = (double)ws[OFF_CE] / (double)Bn;
            out[0] = (float)(celoss + xloss);
        }
    }
}

extern "C" void kernel_launch(void* const* d_in, const int* in_sizes, int n_in,
                              void* d_out, int out_size, void* d_ws, size_t ws_size,
                              hipStream_t stream)
{
    const float* outputs = (const float*)d_in[0];   // [4096,10] f32
    const float* grad    = (const float*)d_in[1];   // [4096,1,64,64] f32
    const int*   y       = (const int*)d_in[2];     // [4096] i32
    float* ws  = (float*)d_ws;
    float* out = (float*)d_out;

    hipMemsetAsync(d_ws, 0, 64, stream);   // cursors, CE, XS, DONE
    pass0_ce_order<<<Bn / 256, 256, 0, stream>>>(outputs, y, ws);
    pass12_fused<<<MAXCH, 256, 0, stream>>>(grad, ws);
    pass34_final<<<NCLS * Dn / 256, 256, 0, stream>>>(ws, out);
}

// Round 7
// 117.357 us; speedup vs baseline: 1.1313x; 1.0085x over previous
//
#include <hip/hip_runtime.h>
#include <math.h>

constexpr int Dn = 4096;     // C*H*W (row length)
constexpr int Bn = 4096;     // batch
constexpr int NCLS = 10;
constexpr int CH = 4;        // rows per chunk == waves per pass12 block
constexpr int NBLK0 = Bn / 256;         // 16 pass0 blocks
constexpr int MAXCH = Bn / CH + NCLS;   // 1034 grid upper bound

// Workspace layout (float/int units). NO pre-zeroing needed:
// every slot is written exactly once by plain stores before being read.
constexpr int OFF_CEB  = 0;      // 16 floats: per-block CE sums
constexpr int OFF_CNT  = 16;     // 16*10 ints: blkcnt[b][c]
constexpr int OFF_XS   = 176;    // 1 float (zeroed by pass0 block 0)
constexpr int OFF_DONE = 177;    // 1 int   (zeroed by pass0 block 0)
constexpr int OFF_ORDB = 192;    // 16*10*256 ints: ORDB[b][c][r]
constexpr int OFF_P    = 41216;  // partials: MAXCH * 4096 floats (16B aligned)

// ---------------------------------------------------------------- pass 0
// CE + argmax + block-local class lists. 16 blocks x 256. NO global atomics.
__global__ __launch_bounds__(256) void pass0_ce_order(
    const float* __restrict__ outputs, const int* __restrict__ y,
    float* __restrict__ ws)
{
    const int t = threadIdx.x;
    const int b = blockIdx.x;
    const int i = b * 256 + t;
    const int w = t >> 6, lane = t & 63;
    int* wsi = (int*)ws;

    __shared__ int hist[NCLS];
    __shared__ float sce[4];
    if (t < NCLS) hist[t] = 0;
    __syncthreads();

    const float* o = outputs + (size_t)i * NCLS;
    float m = o[0]; int am = 0;
    #pragma unroll
    for (int k = 1; k < NCLS; ++k) { float ok = o[k]; if (ok > m) { m = ok; am = k; } }
    float se = 0.f;
    #pragma unroll
    for (int k = 0; k < NCLS; ++k) se += expf(o[k] - m);
    float ce = m + logf(se) - o[y[i]];

    int rank = atomicAdd(&hist[am], 1);              // LDS atomic only
    wsi[OFF_ORDB + (b * NCLS + am) * 256 + rank] = i;

    #pragma unroll
    for (int off = 32; off; off >>= 1) ce += __shfl_down(ce, off, 64);
    if (lane == 0) sce[w] = ce;
    __syncthreads();

    if (t < NCLS) wsi[OFF_CNT + b * NCLS + t] = hist[t];
    if (t == 0) ws[OFF_CEB + b] = sce[0] + sce[1] + sce[2] + sce[3];
    if (b == 0 && t == 32) { ws[OFF_XS] = 0.f; wsi[OFF_DONE] = 0; }
}

// ---------------------------------------------------------------- pass 12
// Fused stats + accumulate, grad read ONCE. One chunk (<=4 same-class rows)
// per block, one row per wave. Chunk map + rank->(block,local) mapping
// derived inline from the 160 block-local counts.
__global__ __launch_bounds__(256) void pass12_fused(
    const float* __restrict__ grad, float* __restrict__ ws)
{
    const int* wsi = (const int*)ws;
    const int t = threadIdx.x, w = t >> 6, lane = t & 63;

    __shared__ int lcnt[NBLK0 * NCLS];   // blkcnt[b][c]
    __shared__ int tot[NCLS];
    if (t < NBLK0 * NCLS) lcnt[t] = wsi[OFF_CNT + t];
    __syncthreads();
    if (t < NCLS) {
        int s = 0;
        #pragma unroll
        for (int bb = 0; bb < NBLK0; ++bb) s += lcnt[bb * NCLS + t];
        tot[t] = s;
    }
    __syncthreads();

    // chunk map: blockIdx.x -> (class c, global start s0, class count cnt)
    int c = -1, s0 = 0, cnt = 0;
    {
        int bidx = (int)blockIdx.x, acc = 0;
        #pragma unroll
        for (int k = 0; k < NCLS; ++k) {
            int n = tot[k];
            int nch = (n + CH - 1) / CH;
            if (c < 0 && bidx < acc + nch) { c = k; s0 = (bidx - acc) * CH; cnt = n; }
            acc += nch;
        }
    }
    if (c < 0) return;                       // uniform per block
    const int m = min(CH, cnt - s0);

    float4 v[16];
    if (w < m) {
        // map global rank r (within class c) -> source pass0 block + local pos
        int idx;
        {
            const int r = s0 + w;
            int pref = 0, src = 0, loc = 0;
            #pragma unroll
            for (int bb = 0; bb < NBLK0; ++bb) {
                int n = lcnt[bb * NCLS + c];
                if (r >= pref && r < pref + n) { src = bb; loc = r - pref; }
                pref += n;
            }
            idx = wsi[OFF_ORDB + (src * NCLS + c) * 256 + loc];
        }
        const float4* row = (const float4*)grad + (size_t)idx * (Dn / 4);
        #pragma unroll
        for (int k = 0; k < 16; ++k) v[k] = row[k * 64 + lane];

        // wave min (butterfly)
        float mn = fminf(fminf(v[0].x, v[0].y), fminf(v[0].z, v[0].w));
        #pragma unroll
        for (int k = 1; k < 16; ++k)
            mn = fminf(mn, fminf(fminf(v[k].x, v[k].y), fminf(v[k].z, v[k].w)));
        #pragma unroll
        for (int off = 1; off < 64; off <<= 1)
            mn = fminf(mn, __shfl_xor(mn, off, 64));

        // wave sum of squares of (g - mn)
        float ss = 0.f;
        #pragma unroll
        for (int k = 0; k < 16; ++k) {
            float dx = v[k].x - mn, dy = v[k].y - mn;
            float dz = v[k].z - mn, dw = v[k].w - mn;
            ss += dx * dx + dy * dy + dz * dz + dw * dw;
        }
        #pragma unroll
        for (int off = 1; off < 64; off <<= 1)
            ss += __shfl_xor(ss, off, 64);

        const float a = 1.0f / sqrtf(ss);    // min-max range cancels under L2
        const float b = -mn * a;
        #pragma unroll
        for (int k = 0; k < 16; ++k) {
            v[k].x = fmaf(v[k].x, a, b);
            v[k].y = fmaf(v[k].y, a, b);
            v[k].z = fmaf(v[k].z, a, b);
            v[k].w = fmaf(v[k].w, a, b);
        }
    } else {
        #pragma unroll
        for (int k = 0; k < 16; ++k) v[k] = make_float4(0.f, 0.f, 0.f, 0.f);
    }

    // 4-wave combine through ONE 16 KB buffer (4 syncs)
    __shared__ float4 buf[1024];
    if (w == 1) {
        #pragma unroll
        for (int k = 0; k < 16; ++k) buf[k * 64 + lane] = v[k];
    }
    __syncthreads();
    if (w == 0) {
        #pragma unroll
        for (int k = 0; k < 16; ++k) {
            float4 u = buf[k * 64 + lane];
            v[k].x += u.x; v[k].y += u.y; v[k].z += u.z; v[k].w += u.w;
        }
    }
    __syncthreads();
    if (w == 3) {
        #pragma unroll
        for (int k = 0; k < 16; ++k) buf[k * 64 + lane] = v[k];
    }
    __syncthreads();
    if (w == 2) {
        #pragma unroll
        for (int k = 0; k < 16; ++k) {
            float4 u = buf[k * 64 + lane];
            v[k].x += u.x; v[k].y += u.y; v[k].z += u.z; v[k].w += u.w;
            buf[k * 64 + lane] = v[k];       // same-wave RMW: safe
        }
    }
    __syncthreads();
    if (w == 0) {
        float4* Pc = (float4*)(ws + OFF_P) + (size_t)blockIdx.x * (Dn / 4);
        #pragma unroll
        for (int k = 0; k < 16; ++k) {
            float4 u = buf[k * 64 + lane];
            v[k].x += u.x; v[k].y += u.y; v[k].z += u.z; v[k].w += u.w;
            Pc[k * 64 + lane] = v[k];
        }
    }
}

// ---------------------------------------------------------------- pass 34
// Reduce chunk partials per class, square, sum; last block finalizes.
__global__ __launch_bounds__(256) void pass34_final(
    float* __restrict__ ws, float* __restrict__ out)
{
    const int t = threadIdx.x;
    const int idx = blockIdx.x * 256 + t;    // 0 .. 40959
    const int c = idx >> 12;                 // class (uniform per block)
    const int j = idx & (Dn - 1);
    const int w = t >> 6, lane = t & 63;
    const int* wsi = (const int*)ws;

    __shared__ int tot[NCLS];
    if (t < NCLS) {
        int s = 0;
        #pragma unroll
        for (int bb = 0; bb < NBLK0; ++bb) s += wsi[OFF_CNT + bb * NCLS + t];
        tot[t] = s;
    }
    __syncthreads();

    int cs = 0, ce2 = 0;
    {
        int acc = 0;
        #pragma unroll
        for (int k = 0; k < NCLS; ++k) {
            int nch = (tot[k] + CH - 1) / CH;
            if (k == c) { cs = acc; ce2 = acc + nch; }
            acc += nch;
        }
    }

    const float* P = ws + OFF_P;
    float s = 0.f;
    int ch = cs;
    for (; ch + 4 <= ce2; ch += 4)
        s += P[(size_t)(ch + 0) * Dn + j] + P[(size_t)(ch + 1) * Dn + j]
           + P[(size_t)(ch + 2) * Dn + j] + P[(size_t)(ch + 3) * Dn + j];
    for (; ch < ce2; ++ch) s += P[(size_t)ch * Dn + j];
    float p = s * s;

    #pragma unroll
    for (int off = 32; off; off >>= 1) p += __shfl_down(p, off, 64);
    __shared__ float sr[4];
    if (lane == 0) sr[w] = p;
    __syncthreads();
    if (t == 0) {
        atomicAdd(&ws[OFF_XS], sr[0] + sr[1] + sr[2] + sr[3]);
        __threadfence();
        int ticket = atomicAdd(&((int*)ws)[OFF_DONE], 1);
        if (ticket == (NCLS * Dn / 256) - 1) {
            float xs = atomicAdd(&ws[OFF_XS], 0.0f);   // coherent read
            double n2 = 0.0;
            #pragma unroll
            for (int k = 0; k < NCLS; ++k) { double nc = (double)tot[k]; n2 += nc * nc; }
            double cesum = 0.0;
            #pragma unroll
            for (int k = 0; k < NBLK0; ++k) cesum += (double)ws[OFF_CEB + k];
            double xloss = (n2 - (double)xs) / (2.0 * (double)Bn);
            out[0] = (float)(cesum / (double)Bn + xloss);
        }
    }
}

extern "C" void kernel_launch(void* const* d_in, const int* in_sizes, int n_in,
                              void* d_out, int out_size, void* d_ws, size_t ws_size,
                              hipStream_t stream)
{
    const float* outputs = (const float*)d_in[0];   // [4096,10] f32
    const float* grad    = (const float*)d_in[1];   // [4096,1,64,64] f32
    const int*   y       = (const int*)d_in[2];     // [4096] i32
    float* ws  = (float*)d_ws;
    float* out = (float*)d_out;

    pass0_ce_order<<<NBLK0, 256, 0, stream>>>(outputs, y, ws);
    pass12_fused<<<MAXCH, 256, 0, stream>>>(grad, ws);
    pass34_final<<<NCLS * Dn / 256, 256, 0, stream>>>(ws, out);
}